// Round 1
// baseline (325.374 us; speedup 1.0000x reference)
//
#include <hip/hip_runtime.h>

// ProjectionPursuitProbe: h' = scale * (h - P G^{-1} P^T h), G = P^T P
// B=8, S=4096, F=1024, R=64. Rows N = 32768.

typedef __attribute__((ext_vector_type(8))) short bf16x8;
typedef __attribute__((ext_vector_type(4))) float f32x4;

#define MFMA_B16(a, b, c) __builtin_amdgcn_mfma_f32_16x16x32_bf16((a), (b), (c), 0, 0, 0)

__device__ __forceinline__ unsigned short bf16bits(float x) {
  union { float f; unsigned u; } v; v.f = x;
  return (unsigned short)((v.u + 0x7fffu + ((v.u >> 16) & 1u)) >> 16);  // RNE
}
__device__ __forceinline__ unsigned pack2(float a, float b) {
  return (unsigned)bf16bits(a) | ((unsigned)bf16bits(b) << 16);
}
__device__ __forceinline__ bf16x8 cvt8(const float* p) {  // 8 consecutive LDS floats -> bf16x8
  f32x4 v0 = *(const f32x4*)p;
  f32x4 v1 = *(const f32x4*)(p + 4);
  bf16x8 r;
  r[0] = (short)bf16bits(v0[0]); r[1] = (short)bf16bits(v0[1]);
  r[2] = (short)bf16bits(v0[2]); r[3] = (short)bf16bits(v0[3]);
  r[4] = (short)bf16bits(v1[0]); r[5] = (short)bf16bits(v1[1]);
  r[6] = (short)bf16bits(v1[2]); r[7] = (short)bf16bits(v1[3]);
  return r;
}

// ---------------- K1: partial Gram matrices, partial[ch] = P[ch*64:(ch+1)*64,:]^T @ same ----
__global__ void pp_gram(const float* __restrict__ P, float* __restrict__ partial) {
  __shared__ float Pl[64][68];
  const int tid = threadIdx.x, ch = blockIdx.x;
  // stage 64 f-rows of P (64x64 fp32)
  #pragma unroll
  for (int u = 0; u < 4; ++u) {
    const int f = tid >> 2, r = (tid & 3) * 16 + 4 * u;
    *(f32x4*)&Pl[f][r] = *(const f32x4*)(P + (size_t)(ch * 64 + f) * 64 + r);
  }
  __syncthreads();
  const int a0 = (tid >> 4) * 4, b0 = (tid & 15) * 4;
  f32x4 acc[4];
  #pragma unroll
  for (int i = 0; i < 4; ++i) acc[i] = (f32x4){0.f, 0.f, 0.f, 0.f};
  for (int k = 0; k < 64; ++k) {
    f32x4 av = *(const f32x4*)&Pl[k][a0];
    f32x4 bv = *(const f32x4*)&Pl[k][b0];
    #pragma unroll
    for (int i = 0; i < 4; ++i) acc[i] += av[i] * bv;
  }
  #pragma unroll
  for (int i = 0; i < 4; ++i)
    *(f32x4*)(partial + (size_t)ch * 4096 + (size_t)(a0 + i) * 64 + b0) = acc[i];
}

// ---------------- K2: G = sum partials; W = G^{-1} via in-place Gauss-Jordan (SPD, no pivot) --
__global__ void pp_invert(const float* __restrict__ partial, float* __restrict__ W) {
  __shared__ float A[64][68];
  const int tid = threadIdx.x;
  const int i = tid >> 2, q = tid & 3, q16 = (tid & 3) * 16;
  #pragma unroll
  for (int u = 0; u < 4; ++u) {
    f32x4 s = (f32x4){0.f, 0.f, 0.f, 0.f};
    const int off = i * 64 + q16 + 4 * u;
    for (int p = 0; p < 16; ++p) s += *(const f32x4*)(partial + (size_t)p * 4096 + off);
    *(f32x4*)&A[i][q16 + 4 * u] = s;
  }
  __syncthreads();
  for (int k = 0; k < 64; ++k) {
    const float d = 1.0f / A[k][k];
    const float f = A[i][k];
    f32x4 prs[4], cur[4];
    #pragma unroll
    for (int u = 0; u < 4; ++u) {
      prs[u] = *(const f32x4*)&A[k][q16 + 4 * u];
      cur[u] = *(const f32x4*)&A[i][q16 + 4 * u];
    }
    __syncthreads();  // all reads done before any writes
    const int kl = k - q16;  // pivot column, local to this thread's 16-col slice
    #pragma unroll
    for (int u = 0; u < 4; ++u) {
      f32x4 pv = prs[u] * d;
      if (kl >= u * 4 && kl < u * 4 + 4) { pv[kl - u * 4] = d; cur[u][kl - u * 4] = 0.f; }
      f32x4 res = (i == k) ? pv : (cur[u] - f * pv);
      *(f32x4*)&A[i][q16 + 4 * u] = res;
    }
    __syncthreads();
  }
  #pragma unroll
  for (int u = 0; u < 4; ++u)
    *(f32x4*)(W + (size_t)i * 64 + q16 + 4 * u) = *(const f32x4*)&A[i][q16 + 4 * u];
}

// ---------------- K3: pack P -> Pb (f-major bf16) and Ptb (r-major bf16 transpose) ----------
__global__ void pp_pack(const float* __restrict__ P, unsigned short* __restrict__ Ptb,
                        unsigned short* __restrict__ Pb) {
  const int g = blockIdx.x * 256 + threadIdx.x;  // 16384 threads x 4 elems
  const int flat = g * 4;
  const int f = flat >> 6, r = flat & 63;
  f32x4 v = *(const f32x4*)(P + flat);
  unsigned short b[4];
  #pragma unroll
  for (int u = 0; u < 4; ++u) b[u] = bf16bits(v[u]);
  unsigned lo = (unsigned)b[0] | ((unsigned)b[1] << 16);
  unsigned hi = (unsigned)b[2] | ((unsigned)b[3] << 16);
  *(unsigned long long*)(Pb + flat) = (unsigned long long)lo | ((unsigned long long)hi << 32);
  #pragma unroll
  for (int u = 0; u < 4; ++u) Ptb[(size_t)(r + u) * 1024 + f] = b[u];
}

// ---------------- K4: fused main kernel, 64 rows per block --------------------------------
__global__ __launch_bounds__(256, 2) void pp_main(
    const float* __restrict__ H, const unsigned short* __restrict__ Ptb,
    const unsigned short* __restrict__ Pb, const float* __restrict__ W,
    float* __restrict__ out) {
  __shared__ unsigned short Ha[64][136];  // bf16 H chunk, pad 136 (=17x8) for banks + 16B align
  __shared__ float Yl[64][68];            // Y = H @ P (fp32)
  __shared__ float Cl[64][68];            // C = Y @ W (fp32)
  __shared__ unsigned short Wl[64][72];   // W bf16 (symmetric -> row-major == B^T layout)
  __shared__ float rowsq[64], dotv[64], scalev[64];

  const int tid = threadIdx.x;
  const int lane = tid & 63, wid = tid >> 6;
  const int c16 = lane & 15, quad = lane >> 4;
  const int strip = wid * 16;
  const int srow = tid >> 2, sg = tid & 3;  // staging: 4 threads/row, 32 f each
  const long row0 = (long)blockIdx.x * 64;

  if (tid < 64) { rowsq[tid] = 0.f; dotv[tid] = 0.f; }
  for (int u = tid; u < 4096; u += 256) Wl[u >> 6][u & 63] = bf16bits(W[u]);

  f32x4 accY[4];
  #pragma unroll
  for (int t = 0; t < 4; ++t) accY[t] = (f32x4){0.f, 0.f, 0.f, 0.f};

  float sqacc = 0.f;
  const float* hrow = H + (row0 + srow) * 1024 + sg * 32;

  // ---- phase 1: Y = H @ P  (K = 1024, chunks of 128) + row sum-of-squares ----
  for (int ch = 0; ch < 8; ++ch) {
    const float* hp = hrow + ch * 128;
    #pragma unroll
    for (int u = 0; u < 8; ++u) {
      f32x4 v = *(const f32x4*)(hp + 4 * u);
      sqacc += v[0] * v[0] + v[1] * v[1] + v[2] * v[2] + v[3] * v[3];
      unsigned lo = pack2(v[0], v[1]), hi = pack2(v[2], v[3]);
      *(unsigned long long*)&Ha[srow][sg * 32 + 4 * u] =
          (unsigned long long)lo | ((unsigned long long)hi << 32);
    }
    __syncthreads();
    #pragma unroll
    for (int it = 0; it < 4; ++it) {
      bf16x8 a = *(const bf16x8*)&Ha[strip + c16][it * 32 + quad * 8];
      const unsigned short* bp = Ptb + (size_t)c16 * 1024 + ch * 128 + it * 32 + quad * 8;
      #pragma unroll
      for (int t = 0; t < 4; ++t) {  // B[k=f][n=r] = P[f][r] = Ptb[r][f], k-contiguous
        bf16x8 b = *(const bf16x8*)(bp + (size_t)t * 16 * 1024);
        accY[t] = MFMA_B16(a, b, accY[t]);
      }
    }
    __syncthreads();
  }
  atomicAdd(&rowsq[srow], sqacc);
  #pragma unroll
  for (int t = 0; t < 4; ++t)
    #pragma unroll
    for (int r = 0; r < 4; ++r)  // D layout: col = lane&15, row = quad*4+reg
      Yl[strip + quad * 4 + r][t * 16 + c16] = accY[t][r];
  __syncthreads();

  // ---- phase 2: C = Y @ W (W symmetric) ----
  f32x4 accC[4];
  #pragma unroll
  for (int t = 0; t < 4; ++t) accC[t] = (f32x4){0.f, 0.f, 0.f, 0.f};
  #pragma unroll
  for (int kk = 0; kk < 2; ++kk) {
    bf16x8 a = cvt8(&Yl[strip + c16][kk * 32 + quad * 8]);
    #pragma unroll
    for (int t = 0; t < 4; ++t) {
      bf16x8 b = *(const bf16x8*)&Wl[t * 16 + c16][kk * 32 + quad * 8];
      accC[t] = MFMA_B16(a, b, accC[t]);
    }
  }
  #pragma unroll
  for (int t = 0; t < 4; ++t)
    #pragma unroll
    for (int r = 0; r < 4; ++r) Cl[strip + quad * 4 + r][t * 16 + c16] = accC[t][r];
  __syncthreads();

  // ---- per-row: dot = y.c = ||proj||^2 ; scale = old/new = sqrt(o2/(o2-dot)) ----
  {
    float d = 0.f;
    #pragma unroll
    for (int u = 0; u < 4; ++u) {
      f32x4 yv = *(const f32x4*)&Yl[srow][sg * 16 + 4 * u];
      f32x4 cv = *(const f32x4*)&Cl[srow][sg * 16 + 4 * u];
      d += yv[0] * cv[0] + yv[1] * cv[1] + yv[2] * cv[2] + yv[3] * cv[3];
    }
    atomicAdd(&dotv[srow], d);
  }
  __syncthreads();
  if (tid < 64) {
    float o2 = rowsq[tid];
    float n2 = fmaxf(o2 - dotv[tid], 1e-30f);
    scalev[tid] = sqrtf(o2 / n2);
  }
  __syncthreads();

  // ---- phase 3: out = (H - C @ P^T) * scale, exact copy for s==0 rows ----
  bf16x8 ca0 = cvt8(&Cl[strip + c16][quad * 8]);        // A[m][k=r], k in [0,32)
  bf16x8 ca1 = cvt8(&Cl[strip + c16][32 + quad * 8]);   // k in [32,64)
  float sc[4]; long rg[4]; bool fs[4];
  #pragma unroll
  for (int r = 0; r < 4; ++r) {
    const int m = strip + quad * 4 + r;
    sc[r] = scalev[m];
    rg[r] = row0 + m;
    fs[r] = ((rg[r] & 4095) == 0);  // s == 0 rows pass through exactly
  }
  for (int ft = 0; ft < 64; ++ft) {
    const unsigned short* bp = Pb + (size_t)(ft * 16 + c16) * 64 + quad * 8;
    bf16x8 b0 = *(const bf16x8*)bp;         // B[k=r][n=f] = P[f][r], r-contiguous
    bf16x8 b1 = *(const bf16x8*)(bp + 32);
    f32x4 acc = (f32x4){0.f, 0.f, 0.f, 0.f};
    acc = MFMA_B16(ca0, b0, acc);
    acc = MFMA_B16(ca1, b1, acc);
    const int f = ft * 16 + c16;
    #pragma unroll
    for (int r = 0; r < 4; ++r) {
      const long idx = rg[r] * 1024 + f;
      const float h = H[idx];  // block-local re-read: L2/L3 hit
      out[idx] = fs[r] ? h : (h - acc[r]) * sc[r];
    }
  }
}

extern "C" void kernel_launch(void* const* d_in, const int* in_sizes, int n_in,
                              void* d_out, int out_size, void* d_ws, size_t ws_size,
                              hipStream_t stream) {
  const float* H = (const float*)d_in[0];   // 8*4096*1024 fp32
  const float* P = (const float*)d_in[1];   // 1024*64 fp32
  float* out = (float*)d_out;
  float* ws = (float*)d_ws;
  // ws layout: W (4096 f32) | partialG (16*4096 f32) | Ptb (65536 bf16) | Pb (65536 bf16)
  float* W = ws;
  float* partial = ws + 4096;
  unsigned short* Ptb = (unsigned short*)(ws + 4096 + 16 * 4096);
  unsigned short* Pb = Ptb + 65536;

  pp_gram<<<16, 256, 0, stream>>>(P, partial);
  pp_invert<<<1, 256, 0, stream>>>(partial, W);
  pp_pack<<<64, 256, 0, stream>>>(P, Ptb, Pb);
  pp_main<<<512, 256, 0, stream>>>(H, Ptb, Pb, W, out);
}